// Round 1
// baseline (562.377 us; speedup 1.0000x reference)
//
#include <hip/hip_runtime.h>
#include <hip/hip_bf16.h>

#define NB 2048
#define NF 6144
#define ND 768

typedef __attribute__((ext_vector_type(4))) __bf16 bf16x4;
typedef __attribute__((ext_vector_type(8))) __bf16 bf16x8;
typedef __attribute__((ext_vector_type(4))) float f32x4;

// out[b,d] = sum_l bias[l,d]  (also clears the 0xAA poison deterministically)
__global__ __launch_bounds__(256) void bias_init_kernel(
    const float* __restrict__ bias, const int* __restrict__ lidx,
    float* __restrict__ out) {
  int n = lidx[0] + 1;
  int i = blockIdx.x * 256 + threadIdx.x;
  if (i >= NB * ND) return;
  int d = i % ND;
  float s = 0.f;
  for (int l = 0; l < n; ++l) s += bias[l * ND + d];
  out[i] = s;
}

// One block: 128(b) x 128(d) tile for one layer l; K-loop over F in steps of 64.
// LDS layout (both A and B): row-major 128 rows x 64 bf16 (128 B rows), with
// 16-byte-block XOR swizzle: byte = row*128 + (((k>>3) ^ (row&7))<<4) + (k&7)*2
// -> fragment ds_read_b128 across 16 rows is 2-way (free), staging writes are
// at the bank-throughput minimum.
__global__ __launch_bounds__(256) void gemm_kernel(
    const float* __restrict__ acts, const float* __restrict__ W,
    const int* __restrict__ lidx, float* __restrict__ out) {
  const int l = blockIdx.z;
  if (l > lidx[0]) return;  // uniform exit before any barrier

  const int brow = blockIdx.x * 128;
  const int ncol = blockIdx.y * 128;

  __shared__ char cA[128 * 128];  // 128 rows(b) x 64 bf16(k)
  __shared__ char cB[128 * 128];  // 128 rows(d) x 64 bf16(k)

  const int tid = threadIdx.x;
  const int lane = tid & 63;
  const int wid = tid >> 6;
  const int wrow = (wid >> 1) * 64;  // wave's 64x64 sub-tile
  const int wcol = (wid & 1) * 64;

  f32x4 acc[4][4];
#pragma unroll
  for (int i = 0; i < 4; ++i)
#pragma unroll
    for (int j = 0; j < 4; ++j) acc[i][j] = (f32x4){0.f, 0.f, 0.f, 0.f};

  // A staging: thread -> (row=tid>>4 (+16 per pass), 4 consecutive k)
  const int arow = tid >> 4;       // 0..15
  const int ak = (tid & 15) * 4;   // 0,4,...,60
  // B staging: thread -> (d = tid&127, block of 8 k), 4 passes
  const int bd = tid & 127;
  const int bkb0 = tid >> 7;       // 0..1

  const float* Aptr = acts + (size_t)l * NB * NF + (size_t)(brow + arow) * NF + ak;
  const float* Bptr = W + (size_t)l * NF * ND + (size_t)(bkb0 * 8) * ND + (ncol + bd);

  const int blkA = (ak >> 3) ^ (arow & 7);           // invariant: (row+16p)&7 == arow&7
  char* wA = cA + arow * 128 + (blkA << 4) + ((ak & 7) << 1);

  for (int kt = 0; kt < NF / 64; ++kt) {
    // ---- issue all global loads for this K-slab (overlaps the barrier) ----
    float4 av[8];
#pragma unroll
    for (int p = 0; p < 8; ++p)
      av[p] = *(const float4*)(Aptr + (size_t)p * (16 * NF));

    float bv[4][8];
#pragma unroll
    for (int p = 0; p < 4; ++p)
#pragma unroll
      for (int j = 0; j < 8; ++j)
        bv[p][j] = Bptr[(size_t)(p * 16 + j) * ND];

    __syncthreads();  // previous iteration's fragment reads are done

    // ---- convert + LDS write, A: b64 per pass ----
#pragma unroll
    for (int p = 0; p < 8; ++p) {
      bf16x4 h;
      h[0] = (__bf16)av[p].x; h[1] = (__bf16)av[p].y;
      h[2] = (__bf16)av[p].z; h[3] = (__bf16)av[p].w;
      *(bf16x4*)(wA + p * 2048) = h;  // row advances by 16 -> +2048 B
    }
    // ---- B: transpose in regs, b128 per pass ----
#pragma unroll
    for (int p = 0; p < 4; ++p) {
      const int kb8 = bkb0 + 2 * p;
      bf16x8 h;
#pragma unroll
      for (int j = 0; j < 8; ++j) h[j] = (__bf16)bv[p][j];
      *(bf16x8*)(cB + bd * 128 + ((kb8 ^ (bd & 7)) << 4)) = h;
    }

    __syncthreads();

    // ---- MFMA: 2 k-steps of 32, 4x4 fragments ----
#pragma unroll
    for (int s = 0; s < 2; ++s) {
      const int kb = s * 4 + (lane >> 4);  // 16B-block index of this lane's k
      bf16x8 aF[4], bF[4];
#pragma unroll
      for (int mi = 0; mi < 4; ++mi) {
        const int row = wrow + mi * 16 + (lane & 15);
        aF[mi] = *(const bf16x8*)(cA + row * 128 + ((kb ^ (row & 7)) << 4));
      }
#pragma unroll
      for (int ni = 0; ni < 4; ++ni) {
        const int row = wcol + ni * 16 + (lane & 15);
        bF[ni] = *(const bf16x8*)(cB + row * 128 + ((kb ^ (row & 7)) << 4));
      }
#pragma unroll
      for (int mi = 0; mi < 4; ++mi)
#pragma unroll
        for (int ni = 0; ni < 4; ++ni)
          acc[mi][ni] = __builtin_amdgcn_mfma_f32_16x16x32_bf16(
              aF[mi], bF[ni], acc[mi][ni], 0, 0, 0);
    }

    Aptr += 64;
    Bptr += (size_t)64 * ND;
  }

  // ---- epilogue: atomic accumulate into out (12 layer-blocks collide) ----
  // C/D layout (m89-verified): col = lane&15, row = (lane>>4)*4 + j
  const int orow = brow + wrow + ((lane >> 4) << 2);
  const int ocol = ncol + wcol + (lane & 15);
#pragma unroll
  for (int mi = 0; mi < 4; ++mi)
#pragma unroll
    for (int ni = 0; ni < 4; ++ni)
#pragma unroll
      for (int j = 0; j < 4; ++j)
        atomicAdd(out + (size_t)(orow + mi * 16 + j) * ND + (ocol + ni * 16),
                  acc[mi][ni][j]);
}

extern "C" void kernel_launch(void* const* d_in, const int* in_sizes, int n_in,
                              void* d_out, int out_size, void* d_ws, size_t ws_size,
                              hipStream_t stream) {
  const float* acts = (const float*)d_in[0];
  const float* W    = (const float*)d_in[1];
  const float* bias = (const float*)d_in[2];
  const int*   lidx = (const int*)d_in[3];
  float* out = (float*)d_out;

  const int L = in_sizes[0] / (NB * NF);  // 12

  bias_init_kernel<<<dim3((NB * ND + 255) / 256), 256, 0, stream>>>(bias, lidx, out);
  gemm_kernel<<<dim3(NB / 128, ND / 128, L), 256, 0, stream>>>(acts, W, lidx, out);
}